// Round 1
// baseline (104.885 us; speedup 1.0000x reference)
//
#include <hip/hip_runtime.h>

// CARAFE: features [B=2, h=64, w=64, C0=256] f32, masks [B, H=128, W=128, 25] f32,
// k=5, group=1. Nearest-upsample (half-pixel, 2x) == Y//2.
// out[b,Y,X,c] = sum_{di,dj} M[b,Y,X,di*5+dj] * F[b, Y/2+di-2, X/2+dj-2, c] (zero pad).
//
// R5 (occupancy round):
//  - rocprof showed the top dispatches are the harness poison-fill (44.8us);
//    carafe itself is ~33us, ~10x above all throughput rooflines (VALU 2.7us,
//    HBM 7us, L2 4us) => latency-bound at 4 waves/SIMD (grid 4096 waves / 1024
//    SIMDs). Occupancy was structurally capped by the grid, not by resources.
//  - Channel-split x2: each wave keeps the 2-pixel / 5x6 tap-union structure
//    but covers 128 channels (float2 per lane) instead of 256 (float4).
//    This is the only split that duplicates ZERO feature bytes (the halves
//    read disjoint channels). 2048 blocks * 4 waves = 8192 waves = 8/SIMD,
//    exactly one full residency round. Per-wave: 30 float2 loads (512B/instr,
//    still coalesced), 400 FMAs, acc = 16 VGPRs.
//  - __launch_bounds__(256, 8): cap VGPRs at 64 so 8 blocks/CU actually
//    co-reside. With float2 acc+staging this should fit without spill
//    (post-mortem: check VGPR_Count <= 64, scratch == 0).
//  - XCD swizzle kept: 16 contiguous rows per XCD (~1.3 MB feat working set
//    incl. halo, both channel halves -> same XCD, fits 4 MiB L2). Mask reads
//    double (both halves read the same 25 weights) but stay L2-local.
//  - Body stays branchless wrt data (clamp + 0/1 scale); t<=4 / t>=1 guards
//    compile-time after full unroll.

#define C0   256
#define HLO  64
#define WLO  64
#define HHI  128
#define WHI  128
#define K    5
#define KK   25

__global__ __launch_bounds__(256, 8) void carafe_kernel(
    const float* __restrict__ feat,   // [B, 64, 64, 256]
    const float* __restrict__ mask,   // [B, 128, 128, 25]
    float* __restrict__ out)          // [B, 128, 128, 256]
{
    // --- scalar (wave-uniform) tile coordinates ---
    // bid bits: [2:0]=xcd slot, then i = bid>>3 with
    //   i[0]   = ch   (channel half)
    //   i[4:1] = rloc (row within this XCD's 16-row band)
    //   i[7:5] = xblk (x tile)
    const int wv   = __builtin_amdgcn_readfirstlane(threadIdx.x >> 6); // 0..3
    const int bid  = blockIdx.x;          // 0..2047
    const int xcd  = bid & 7;             // round-robin XCD slot (heuristic)
    const int i    = bid >> 3;            // 0..255
    const int ch   = i & 1;               // channel half 0/1
    const int rloc = (i >> 1) & 15;       // 0..15
    const int xblk = i >> 5;              // 0..7
    const int r    = xcd * 16 + rloc;     // global row 0..127 (contig per XCD)
    const int b    = r >> 6;
    const int y0   = r & 63;
    const int x0   = xblk * 8 + wv * 2;   // low-res col of first quad
    const int lane = threadIdx.x & 63;
    const int c    = ch * 128 + lane * 2; // per-lane channel offset (float2)

    const int Y0 = y0 * 2;
    const int X0 = x0 * 2;

    const float* fbase = feat + (size_t)b * HLO * WLO * C0;
    const float* mrow0 = mask + (size_t)((b * HHI + Y0) * WHI + X0) * KK;
    const float* mrow1 = mrow0 + WHI * KK;

    // acc[row][qq]: output pixel (Y0+row, X0+qq), 2 channels each.
    float2 acc[2][4];
    #pragma unroll
    for (int rr = 0; rr < 2; ++rr)
        #pragma unroll
        for (int qq = 0; qq < 4; ++qq)
            acc[rr][qq] = make_float2(0.f, 0.f);

    #pragma unroll
    for (int di = 0; di < K; ++di) {
        const int   y  = y0 + di - 2;
        const int   yc = min(max(y, 0), HLO - 1);
        const float vy = ((unsigned)y < (unsigned)HLO) ? 1.f : 0.f;
        #pragma unroll
        for (int t = 0; t < 6; ++t) {           // tap col x0 + t - 2
            const int   x  = x0 + t - 2;
            const int   xc = min(max(x, 0), WLO - 1);
            const float v  = ((unsigned)x < (unsigned)WLO) ? vy : 0.f;

            float2 f = *(const float2*)(fbase + (size_t)(yc * WLO + xc) * C0 + c);
            f.x *= v; f.y *= v;

            // quad 0 (out cols qq=0,1): dj = t, valid for t<=4  (compile-time)
            if (t <= 4) {
                const int p = di * K + t;
                #pragma unroll
                for (int rr = 0; rr < 2; ++rr) {
                    const float* mr = rr ? mrow1 : mrow0;
                    #pragma unroll
                    for (int qq = 0; qq < 2; ++qq) {
                        const float wgt = mr[qq * KK + p];
                        acc[rr][qq].x = fmaf(f.x, wgt, acc[rr][qq].x);
                        acc[rr][qq].y = fmaf(f.y, wgt, acc[rr][qq].y);
                    }
                }
            }
            // quad 1 (out cols qq=2,3): dj = t-1, valid for t>=1 (compile-time)
            if (t >= 1) {
                const int p = di * K + t - 1;
                #pragma unroll
                for (int rr = 0; rr < 2; ++rr) {
                    const float* mr = rr ? mrow1 : mrow0;
                    #pragma unroll
                    for (int qq = 2; qq < 4; ++qq) {
                        const float wgt = mr[qq * KK + p];
                        acc[rr][qq].x = fmaf(f.x, wgt, acc[rr][qq].x);
                        acc[rr][qq].y = fmaf(f.y, wgt, acc[rr][qq].y);
                    }
                }
            }
        }
    }

    float* ob = out + (size_t)((b * HHI + Y0) * WHI + X0) * C0 + c;
    #pragma unroll
    for (int rr = 0; rr < 2; ++rr)
        #pragma unroll
        for (int qq = 0; qq < 4; ++qq)
            *(float2*)(ob + (size_t)(rr * WHI + qq) * C0) = acc[rr][qq];
}

extern "C" void kernel_launch(void* const* d_in, const int* in_sizes, int n_in,
                              void* d_out, int out_size, void* d_ws, size_t ws_size,
                              hipStream_t stream) {
    const float* feat = (const float*)d_in[0];   // 2*64*64*256
    const float* mask = (const float*)d_in[1];   // 2*128*128*25
    float* out = (float*)d_out;                  // 2*128*128*256

    // 2 batches * 64 rows * 8 x-blocks * 2 channel-halves = 2048 blocks;
    // 4 waves/block, each wave = 2 low-res pixels x 128 channels.
    carafe_kernel<<<2048, 256, 0, stream>>>(feat, mask, out);
}

// Round 2
// 79.936 us; speedup vs baseline: 1.3121x; 1.3121x over previous
//
#include <hip/hip_runtime.h>

// CARAFE: features [B=2, h=64, w=64, C0=256] f32, masks [B, H=128, W=128, 25] f32,
// k=5, group=1. Nearest-upsample (half-pixel, 2x) == Y//2.
// out[b,Y,X,c] = sum_{di,dj} M[b,Y,X,di*5+dj] * F[b, Y/2+di-2, X/2+dj-2, c] (zero pad).
//
// R6 (LDS staging round):
//  - R5 post-mortem: __launch_bounds__(256,8) forced a 64-VGPR cap; the 30
//    in-flight float loads spilled/serialized -> 78us -> 105us. Reverted.
//  - R4 kernel (~33us) is ~4x above rooflines (VALU 2.7us, HBM 7us, L2 4us):
//    latency-bound on 30 dependent global loads per wave held in VGPRs.
//  - Fix: stage each block's tap UNION (5 rows x 12 cols x 1KB = 60KB) into
//    LDS via __builtin_amdgcn_global_load_lds (fire-and-forget, no VGPR
//    round-trip; compiler never auto-emits it). Each of the 60 issues moves
//    one low-res pixel: lane i loads channels 4i..4i+3 (16B) from global,
//    lands at ldsbase + lane*16 (linear dest, as the HW requires).
//    This also halves L1/L2 feature traffic (60 px staged vs 4 waves x 30).
//  - Compute identical to R4 but taps come from LDS (ds_read_b128, contiguous
//    1KB per tap -> conflict-free). VGPR need drops to ~acc(32)+fragments.
//  - Zero-pad semantics: staging uses CLAMPED addresses; compute multiplies by
//    v in {0,1} exactly as R4 (same math order -> same absmax).
//  - 60KB static LDS -> 2 blocks/CU resident; single __syncthreads(); the
//    compiler's vmcnt(0) drain before s_barrier is exactly what we want.
//  - XCD-aware swizzle kept: 16 contiguous global rows per XCD (~1.3MB feat
//    working set incl. halo fits the 4MiB per-XCD L2).

#define C0   256
#define HLO  64
#define WLO  64
#define HHI  128
#define WHI  128
#define K    5
#define KK   25

#define TROWS 5
#define TCOLS 12
#define TPX   (TROWS * TCOLS)   // 60 pixels, 60KB

__global__ __launch_bounds__(256) void carafe_kernel(
    const float* __restrict__ feat,   // [B, 64, 64, 256]
    const float* __restrict__ mask,   // [B, 128, 128, 25]
    float* __restrict__ out)          // [B, 128, 128, 256]
{
    __shared__ float smem[TPX * C0];  // 61440 B

    // --- scalar (wave-uniform) tile coordinates (same mapping as R4) ---
    const int wv   = __builtin_amdgcn_readfirstlane(threadIdx.x >> 6); // 0..3
    const int bid  = blockIdx.x;          // 0..1023
    const int xcd  = bid & 7;             // round-robin XCD slot (heuristic)
    const int i    = bid >> 3;            // 0..127
    const int r    = xcd * 16 + (i & 15); // global row 0..127 (contig per XCD)
    const int xblk = i >> 4;              // 0..7
    const int b    = r >> 6;
    const int y0   = r & 63;
    const int xb0  = xblk * 8;            // first low-res col of this block
    const int lane = threadIdx.x & 63;
    const int c    = lane * 4;            // per-lane channel offset

    const float* fbase = feat + (size_t)b * HLO * WLO * C0;

    // ---- stage 5x12 tap-union tile into LDS ----
    // tile pixel tp -> (row = tp/12, col = tp%12); source y = y0-2+row (clamp),
    // x = xb0-2+col (clamp). One issue = one 1KB pixel (64 lanes x 16B).
    #pragma unroll
    for (int j = 0; j < 15; ++j) {
        const int tp  = wv + 4 * j;          // wave-uniform, covers 0..59
        const int row = tp / TCOLS;
        const int col = tp % TCOLS;
        const int yc  = min(max(y0 - 2 + row, 0), HLO - 1);
        const int xc  = min(max(xb0 - 2 + col, 0), WLO - 1);
        const float* src = fbase + (size_t)(yc * WLO + xc) * C0 + c; // per-lane
        __builtin_amdgcn_global_load_lds(
            (const __attribute__((address_space(1))) unsigned int*)src,
            (__attribute__((address_space(3))) unsigned int*)&smem[tp * C0],
            16, 0, 0);
    }
    __syncthreads();

    // ---- compute: identical structure to R4, taps from LDS ----
    const int x0 = xb0 + 2 * wv;          // low-res col of first quad
    const int cw = 2 * wv;                // tile-local col of first quad
    const int Y0 = y0 * 2;
    const int X0 = x0 * 2;

    const float* mrow0 = mask + (size_t)((b * HHI + Y0) * WHI + X0) * KK;
    const float* mrow1 = mrow0 + WHI * KK;

    float4 acc[2][4];
    #pragma unroll
    for (int rr = 0; rr < 2; ++rr)
        #pragma unroll
        for (int qq = 0; qq < 4; ++qq)
            acc[rr][qq] = make_float4(0.f, 0.f, 0.f, 0.f);

    #pragma unroll
    for (int di = 0; di < K; ++di) {
        const int   y  = y0 + di - 2;
        const float vy = ((unsigned)y < (unsigned)HLO) ? 1.f : 0.f;
        #pragma unroll
        for (int t = 0; t < 6; ++t) {         // tap col x0 + t - 2
            const int   x = x0 + t - 2;
            const float v = ((unsigned)x < (unsigned)WLO) ? vy : 0.f;

            float4 f = *(const float4*)&smem[(di * TCOLS + cw + t) * C0 + c];
            f.x *= v; f.y *= v; f.z *= v; f.w *= v;

            // quad 0 (out cols qq=0,1): dj = t, valid for t<=4 (compile-time)
            if (t <= 4) {
                const int p = di * K + t;
                #pragma unroll
                for (int rr = 0; rr < 2; ++rr) {
                    const float* mr = rr ? mrow1 : mrow0;
                    #pragma unroll
                    for (int qq = 0; qq < 2; ++qq) {
                        const float wgt = mr[qq * KK + p];
                        acc[rr][qq].x = fmaf(f.x, wgt, acc[rr][qq].x);
                        acc[rr][qq].y = fmaf(f.y, wgt, acc[rr][qq].y);
                        acc[rr][qq].z = fmaf(f.z, wgt, acc[rr][qq].z);
                        acc[rr][qq].w = fmaf(f.w, wgt, acc[rr][qq].w);
                    }
                }
            }
            // quad 1 (out cols qq=2,3): dj = t-1, valid for t>=1 (compile-time)
            if (t >= 1) {
                const int p = di * K + t - 1;
                #pragma unroll
                for (int rr = 0; rr < 2; ++rr) {
                    const float* mr = rr ? mrow1 : mrow0;
                    #pragma unroll
                    for (int qq = 2; qq < 4; ++qq) {
                        const float wgt = mr[qq * KK + p];
                        acc[rr][qq].x = fmaf(f.x, wgt, acc[rr][qq].x);
                        acc[rr][qq].y = fmaf(f.y, wgt, acc[rr][qq].y);
                        acc[rr][qq].z = fmaf(f.z, wgt, acc[rr][qq].z);
                        acc[rr][qq].w = fmaf(f.w, wgt, acc[rr][qq].w);
                    }
                }
            }
        }
    }

    float* ob = out + (size_t)((b * HHI + Y0) * WHI + X0) * C0 + c;
    #pragma unroll
    for (int rr = 0; rr < 2; ++rr)
        #pragma unroll
        for (int qq = 0; qq < 4; ++qq)
            *(float4*)(ob + (size_t)(rr * WHI + qq) * C0) = acc[rr][qq];
}

extern "C" void kernel_launch(void* const* d_in, const int* in_sizes, int n_in,
                              void* d_out, int out_size, void* d_ws, size_t ws_size,
                              hipStream_t stream) {
    const float* feat = (const float*)d_in[0];   // 2*64*64*256
    const float* mask = (const float*)d_in[1];   // 2*128*128*25
    float* out = (float*)d_out;                  // 2*128*128*256

    // 2 batches * 64 rows * 8 x-blocks = 1024 blocks; 4 waves/block,
    // each wave = 2 low-res pixels (2x4 output pixels), taps via LDS union.
    carafe_kernel<<<1024, 256, 0, stream>>>(feat, mask, out);
}